// Round 1
// baseline (614.783 us; speedup 1.0000x reference)
//
#include <hip/hip_runtime.h>
#include <hip/hip_bf16.h>

#define NUM_CLASSES 21
#define CHANNELS 256
#define CPAD 257            // 257 % 32 == 1 -> bank = (k + c) % 32, spreads labels across banks
#define B_SZ 16
#define HF 128
#define WF 128
#define HL 512
#define WL 512
#define PIX_PER_BLOCK 512   // 2 pixels per thread, 256 threads
#define TILES_PER_B (HF * WF / PIX_PER_BLOCK)  // 32

// Accumulate per-class channel sums and pixel counts.
// Grid: 16 * 32 = 512 blocks, 256 threads.
__global__ __launch_bounds__(256) void protos_accum_kernel(
    const float* __restrict__ feats,   // [16][256][128][128]
    const int*   __restrict__ labels,  // [16][512][512]
    float* __restrict__ sums,          // [21][256] (d_ws)
    float* __restrict__ counts)        // [21]      (d_ws)
{
    __shared__ float acc[NUM_CLASSES][CPAD];
    __shared__ float cnt[NUM_CLASSES];

    const int t = threadIdx.x;

    // zero LDS accumulators
    for (int i = t; i < NUM_CLASSES * CPAD; i += 256) ((float*)acc)[i] = 0.0f;
    if (t < NUM_CLASSES) cnt[t] = 0.0f;
    __syncthreads();

    const int b    = blockIdx.x >> 5;          // / TILES_PER_B
    const int tile = blockIdx.x & 31;
    const int base = tile * PIX_PER_BLOCK;     // contiguous pixel range in the 128x128 plane

    const int p0 = base + 2 * t;
    const int p1 = p0 + 1;
    const int h0 = p0 >> 7, w0 = p0 & 127;
    const int h1 = p1 >> 7, w1 = p1 & 127;

    // nearest resize: src = dst * 4 (512/128)
    const int l0 = labels[(size_t)b * (HL * WL) + (size_t)(h0 * 4) * WL + w0 * 4];
    const int l1 = labels[(size_t)b * (HL * WL) + (size_t)(h1 * 4) * WL + w1 * 4];

    atomicAdd(&cnt[l0], 1.0f);
    atomicAdd(&cnt[l1], 1.0f);

    const float* fbase = feats + (size_t)b * CHANNELS * (HF * WF) + base + 2 * t;

    #pragma unroll 4
    for (int c = 0; c < CHANNELS; ++c) {
        const float2 v = *(const float2*)(fbase + (size_t)c * (HF * WF));
        atomicAdd(&acc[l0][c], v.x);
        atomicAdd(&acc[l1][c], v.y);
    }
    __syncthreads();

    // flush block-private accumulators to global
    for (int i = t; i < NUM_CLASSES * CHANNELS; i += 256) {
        const int k = i >> 8;       // / 256
        const int c = i & 255;
        atomicAdd(&sums[i], acc[k][c]);
    }
    if (t < NUM_CLASSES) atomicAdd(&counts[t], cnt[t]);
}

// Grid: 21 blocks x 256 threads. out = [21*256 protos][21 counts]
__global__ __launch_bounds__(256) void protos_finalize_kernel(
    const float* __restrict__ sums,
    const float* __restrict__ counts,
    float* __restrict__ out)
{
    const int k = blockIdx.x;
    const int c = threadIdx.x;
    const float cn = counts[k];
    const float p = (cn > 0.0f) ? (sums[k * CHANNELS + c] / fmaxf(cn, 1.0f)) : 0.0f;
    out[k * CHANNELS + c] = p;
    if (c == 0) out[NUM_CLASSES * CHANNELS + k] = cn;
}

extern "C" void kernel_launch(void* const* d_in, const int* in_sizes, int n_in,
                              void* d_out, int out_size, void* d_ws, size_t ws_size,
                              hipStream_t stream) {
    const float* feats  = (const float*)d_in[0];
    const int*   labels = (const int*)d_in[1];
    float* sums   = (float*)d_ws;                       // [21*256]
    float* counts = sums + NUM_CLASSES * CHANNELS;      // [21]
    float* out    = (float*)d_out;

    // zero the workspace accumulators (harness poisons d_ws before every call)
    hipMemsetAsync(d_ws, 0, (NUM_CLASSES * CHANNELS + NUM_CLASSES) * sizeof(float), stream);

    dim3 grid(B_SZ * TILES_PER_B);   // 512
    dim3 block(256);
    protos_accum_kernel<<<grid, block, 0, stream>>>(feats, labels, sums, counts);

    protos_finalize_kernel<<<dim3(NUM_CLASSES), dim3(CHANNELS), 0, stream>>>(sums, counts, out);
}